// Round 5
// baseline (588.092 us; speedup 1.0000x reference)
//
#include <hip/hip_runtime.h>
#include <cstdint>
#include <cstddef>

#define NNODES 100000
#define NEDGES 1600000
#define DIM 128
#define NREL 8
#define NSEG (NNODES * NREL)                       // 800,000 segments
#define SCAN_BLK 2048
#define NSCAN ((NSEG + SCAN_BLK - 1) / SCAN_BLK)   // 391 scan blocks
#define NKT 36                                     // 1152 / 32 K-steps
#define A16ROW 1160                                // f16 LDS row stride (ushorts)
#define CVT4 (NNODES * DIM / 4)                    // 3,200,000 float4 groups
#define CVT_BLKS ((CVT4 + 255) / 256)              // 12,500
#define PACK_UNITS (NKT * 8 * 2)                   // 576 64-lane pack units
#define PACK_BLKS ((PACK_UNITS + 3) / 4)           // 144

typedef float f32x4 __attribute__((ext_vector_type(4)));
typedef short short4v __attribute__((ext_vector_type(4)));
typedef short short8 __attribute__((ext_vector_type(8)));
typedef _Float16 half4v __attribute__((ext_vector_type(4)));
typedef _Float16 half8 __attribute__((ext_vector_type(8)));

__device__ inline float h2f(unsigned short u) {
    return (float)__builtin_bit_cast(_Float16, u);
}
__device__ inline unsigned short f2h(float f) {
    return __builtin_bit_cast(unsigned short, (_Float16)f);
}

// --------------------------------------- count + cvt + weight-pack (fused) --
__global__ __launch_bounds__(256) void count_cvt(const int* __restrict__ dst,
                                                 const int* __restrict__ et,
                                                 int* __restrict__ cnt,
                                                 const float* __restrict__ x,
                                                 unsigned short* __restrict__ xh,
                                                 const float* __restrict__ Wrel1,
                                                 const float* __restrict__ Wroot1,
                                                 const float* __restrict__ Wrel2,
                                                 const float* __restrict__ Wroot2,
                                                 unsigned short* __restrict__ Wp1,
                                                 unsigned short* __restrict__ Wp2) {
    int b = blockIdx.x;
    if (b < CVT_BLKS) {
        int gid = b * 256 + threadIdx.x;
        if (gid < NEDGES) atomicAdd(&cnt[dst[gid] * NREL + et[gid]], 1);
        if (gid < CVT4) {
            float4 v = *(const float4*)(x + (size_t)gid * 4);
            ushort4 o = make_ushort4(f2h(v.x), f2h(v.y), f2h(v.z), f2h(v.w));
            *(ushort4*)(xh + (size_t)gid * 4) = o;
        }
        return;
    }
    // weight packing: 4 units per block, 64 lanes per unit
    int unit = (b - CVT_BLKS) * 4 + (threadIdx.x >> 6);
    if (unit >= PACK_UNITS) return;
    int lane = threadIdx.x & 63;
    int bb = unit;
    const float* Wrel = Wrel1;
    const float* Wroot = Wroot1;
    unsigned short* Wp = Wp1;
    if (bb >= NKT * 8) {
        bb -= NKT * 8;
        Wrel = Wrel2; Wroot = Wroot2; Wp = Wp2;
    }
    const int kt = bb >> 3, ht = bb & 7;
    const int col = ht * 16 + (lane & 15);
    const int kbase = kt * 32 + (lane >> 4) * 8;
    unsigned short vals[8];
#pragma unroll
    for (int j = 0; j < 8; ++j) {
        int k = kbase + j;
        float f = (k < 1024) ? Wrel[(size_t)k * 128 + col]
                             : Wroot[(size_t)(k - 1024) * 128 + col];
        vals[j] = f2h(f);
    }
    unsigned short* dstp = Wp + ((size_t)bb * 64 + lane) * 8;
#pragma unroll
    for (int j = 0; j < 8; ++j) dstp[j] = vals[j];
}

// ------------------------------------------------- scan pass1 (+inv fuse) ---
__global__ __launch_bounds__(256) void scan_pass1(const int* __restrict__ cnt,
                                                  int* __restrict__ bsum,
                                                  float* __restrict__ inv) {
    int base = blockIdx.x * SCAN_BLK + threadIdx.x * 8;
    int s = 0;
#pragma unroll
    for (int j = 0; j < 8; ++j) {
        int i = base + j;
        if (i < NSEG) {
            int c = cnt[i];
            s += c;
            inv[i] = 1.0f / (float)(c > 1 ? c : 1);
        }
    }
    __shared__ int ws[4];
    for (int d = 1; d < 64; d <<= 1) s += __shfl_xor(s, d);
    int lane = threadIdx.x & 63, w = threadIdx.x >> 6;
    if (lane == 0) ws[w] = s;
    __syncthreads();
    if (threadIdx.x == 0) bsum[blockIdx.x] = ws[0] + ws[1] + ws[2] + ws[3];
}

__global__ __launch_bounds__(64) void scan_pass2(int* __restrict__ bsum) {
    int lane = threadIdx.x;
    int vals[7];
    int s = 0;
#pragma unroll
    for (int j = 0; j < 7; ++j) {
        int i = lane * 7 + j;
        vals[j] = (i < NSCAN) ? bsum[i] : 0;
        s += vals[j];
    }
    int incl = s;
    for (int d = 1; d < 64; d <<= 1) {
        int u = __shfl_up(incl, d);
        if (lane >= d) incl += u;
    }
    int base = incl - s;
#pragma unroll
    for (int j = 0; j < 7; ++j) {
        int i = lane * 7 + j;
        if (i < NSCAN) bsum[i] = base;
        base += vals[j];
    }
}

__global__ __launch_bounds__(256) void scan_pass3(const int* __restrict__ cnt,
                                                  const int* __restrict__ bsum,
                                                  int* __restrict__ segend) {
    int tid = threadIdx.x;
    int base = blockIdx.x * SCAN_BLK + tid * 8;
    int v[8];
    int s = 0;
#pragma unroll
    for (int j = 0; j < 8; ++j) {
        int i = base + j;
        v[j] = (i < NSEG) ? cnt[i] : 0;
        s += v[j];
    }
    int lane = tid & 63, w = tid >> 6;
    int incl = s;
    for (int d = 1; d < 64; d <<= 1) {
        int u = __shfl_up(incl, d);
        if (lane >= d) incl += u;
    }
    __shared__ int wtot[4];
    if (lane == 63) wtot[w] = incl;
    __syncthreads();
    int wbase = 0;
#pragma unroll
    for (int k = 0; k < 4; ++k)
        if (k < w) wbase += wtot[k];
    int tbase = bsum[blockIdx.x] + wbase + (incl - s);
#pragma unroll
    for (int j = 0; j < 8; ++j) {
        int i = base + j;
        if (i < NSEG) segend[i] = tbase;   // becomes segment END after bucketing
        tbase += v[j];
    }
}

// --------------------------------------------------------------- bucket ----
// einfo[p] = src | (rel << 20)   (src < 2^20)
__global__ __launch_bounds__(256) void bucket_kernel(const int* __restrict__ src,
                                                     const int* __restrict__ dst,
                                                     const int* __restrict__ et,
                                                     int* __restrict__ segend,
                                                     int* __restrict__ einfo) {
    int e = blockIdx.x * 256 + threadIdx.x;
    if (e >= NEDGES) return;
    int seg = dst[e] * NREL + et[e];
    int p = atomicAdd(&segend[seg], 1);
    einfo[p] = src[e] | ((seg & 7) << 20);
}

// ---------------------------------------------------------- fused layer ----
// 512 threads (8 waves), 16 nodes/block, 32 lanes/node, 8 B/lane per edge row.
// Phase 1: TRUE rotated gather pipeline.
//   - trip count wave-uniform (U = max over the two 32-lane halves) so loads
//     issue unconditionally: exact waitcnt semantics, no divergent skipping
//   - loads for chunk k+1 issued BEFORE computing chunk k (full-compute
//     issue->use distance); einfo meta 3 chunks deep (2x int4 per chunk)
//   - dummy/straggler iterations clamp to the last real chunk (L1-hot) and
//     mask compute via m = valid ? 1 : 0 feeding v_fma_mix
//   - live set ~90 VGPR under launch_bounds(512,4) cap 128 -> no scratch
// Phase 2: 8 waves x 1 h-tile, 36 K-steps mfma_f32_16x16x32_f16.
#define QE(QL, QH, U) ((U) == 0 ? (QL).x : (U) == 1 ? (QL).y : (U) == 2 ? (QL).z \
                     : (U) == 3 ? (QL).w : (U) == 4 ? (QH).x : (U) == 5 ? (QH).y \
                     : (U) == 6 ? (QH).z : (QH).w)

#define QLOAD(QL, QH, JQ) {                                                    \
    const unsigned _qo = (unsigned)(beg + (JQ) * 8) * 4u;                      \
    QL = *(const int4*)(epc + _qo);                                            \
    QH = *(const int4*)(epc + _qo + 16);                                       \
}

#define GISSUE(V, QL, QH)                                                      \
    _Pragma("unroll")                                                          \
    for (int u = 0; u < 8; ++u) {                                              \
        const unsigned _off =                                                  \
            (((unsigned)QE(QL, QH, u) & 0xFFFFFu) << 8) + lo8;                 \
        V[u] = *(const short4v*)(fb + _off);                                   \
    }

#define FLUSH4 {                                                               \
    float sc = __shfl(invv, cur, 32);                                          \
    short4v o;                                                                 \
    _Pragma("unroll")                                                          \
    for (int j = 0; j < 4; ++j) o[j] = (short)f2h(accv[j] * sc);               \
    *(short4v*)(Arow + cur * DIM + l32 * 4) = o;                               \
    accv = (f32x4){0.f, 0.f, 0.f, 0.f};                                        \
}

#define COMPUTE(V, QL, QH, EB)                                                 \
    _Pragma("unroll")                                                          \
    for (int u = 0; u < 8; ++u) {                                              \
        const int qv = QE(QL, QH, u);                                          \
        const int s = ((unsigned)qv) >> 20;                                    \
        const bool vld = (EB) + u < ecnt;                                      \
        const float mml = vld ? 1.0f : 0.0f;                                   \
        if (vld && s != cur) { FLUSH4 cur = s; }                               \
        const half4v hv = __builtin_bit_cast(half4v, V[u]);                    \
        accv[0] += (float)hv[0] * mml;                                         \
        accv[1] += (float)hv[1] * mml;                                         \
        accv[2] += (float)hv[2] * mml;                                         \
        accv[3] += (float)hv[3] * mml;                                         \
    }

__global__ __launch_bounds__(512, 4) void fused_layer(
    const unsigned short* __restrict__ feat,   // f16 [N][128]
    const int* __restrict__ segend,
    const int* __restrict__ einfo,             // padded: 64B zeros past NEDGES
    const unsigned short* __restrict__ Wp,     // packed f16 B-frags
    const float* __restrict__ bias,
    const float* __restrict__ inv,
    unsigned short* __restrict__ out,          // f16 [N][128] (ignored in head mode)
    const float* __restrict__ outw,            // non-null => head mode
    const float* __restrict__ outb,
    float* __restrict__ head_out) {
    __shared__ __align__(16) unsigned short A16[16 * A16ROW + 8];
    const int tid = threadIdx.x;
    const int blk = blockIdx.x;
    const int g = tid >> 5, l32 = tid & 31;    // 16 groups of 32 lanes

    // --- segment metadata (longest dependency chain: issue first) ---
    const int n = blk * 16 + g;
    const int segbase = n * NREL;
    const int se = segend[segbase + (l32 & 7)];
    const float invv = inv[segbase + (l32 & 7)];
    int prev = 0;
    if (l32 == 0) prev = (segbase == 0) ? 0 : segend[segbase - 1];

    // root row load (independent; overlaps segend)
    const short4v rootv =
        *(const short4v*)(feat + ((size_t)blk * 16 + g) * DIM + l32 * 4);

    prev = __shfl(prev, 0, 32);
    const int beg = prev;
    const int end = __shfl(se, 7, 32);
    const int ecnt = end - beg;

    unsigned short* Arow = &A16[g * A16ROW];

    // stage root row; zero empty relation rows
    *(short4v*)(Arow + 1024 + l32 * 4) = rootv;
    {
        int b = prev;
#pragma unroll
        for (int r = 0; r < 8; ++r) {
            int er = __shfl(se, r, 32);
            if (er == b) {
                short4v z = {0, 0, 0, 0};
                *(short4v*)(Arow + r * DIM + l32 * 4) = z;
            }
            b = er;
        }
    }

    // wave-uniform trip count
    const int nch = (ecnt + 7) >> 3;           // chunks for this half
    const int nchm1 = (nch > 0) ? (nch - 1) : 0;
    int U = nch;
    {
        int Uo = __shfl_xor(U, 32);
        U = U > Uo ? U : Uo;
        U = __builtin_amdgcn_readfirstlane(U);
    }

    if (U > 0) {
        const char* fb = (const char*)feat;
        const char* epc = (const char*)einfo;
        const unsigned lo8 = (unsigned)(l32 * 8);

        int4 qcl, qch, qal, qah, qbl, qbh;
        QLOAD(qcl, qch, 0)                                 // q(0)
        { int c = (1 < nch) ? 1 : nchm1; QLOAD(qal, qah, c) }   // q(1)
        { int c = (2 < nch) ? 2 : nchm1; QLOAD(qbl, qbh, c) }   // q(2)

        int cur = ((unsigned)qcl.x) >> 20;
        f32x4 accv = {0.f, 0.f, 0.f, 0.f};

        short4v vC[8];
        GISSUE(vC, qcl, qch)                               // v(0) in flight

        for (int j = 0; j < U; ++j) {
            __builtin_amdgcn_sched_barrier(0);
            // issue gathers for chunk j+1 (clamped meta already in qa)
            short4v vN[8];
            GISSUE(vN, qal, qah)
            // issue meta for chunk j+3 (clamped)
            int jq = j + 3; jq = (jq < nch) ? jq : nchm1;
            int4 qnl, qnh;
            QLOAD(qnl, qnh, jq)
            __builtin_amdgcn_sched_barrier(0);
            // compute chunk j
            const int ebv = j * 8;
            COMPUTE(vC, qcl, qch, ebv)
            // rotate
            qcl = qal; qch = qah; qal = qbl; qah = qbh; qbl = qnl; qbh = qnh;
#pragma unroll
            for (int u = 0; u < 8; ++u) vC[u] = vN[u];
        }
        if (ecnt > 0) { FLUSH4 }                           // final flush
    }
    __syncthreads();

    // ---- phase 2: MFMA, 8 waves x 1 h-tile ----
    const int lane = tid & 63;
    const int w = tid >> 6;                 // wave id == h-tile id (0..7)
    const int m = lane & 15, kq = lane >> 4;
    const unsigned short* arow = &A16[m * A16ROW + kq * 8];
    const unsigned short* bb0 = Wp + ((size_t)w * 64 + lane) * 8;

    f32x4 acc0 = {0.f, 0.f, 0.f, 0.f};
#pragma unroll 6
    for (int kt = 0; kt < NKT; ++kt) {
        short8 a = *(const short8*)(arow + kt * 32);
        short8 b0 = *(const short8*)(bb0 + (size_t)kt * 4096);
        acc0 = __builtin_amdgcn_mfma_f32_16x16x32_f16(
            __builtin_bit_cast(half8, a), __builtin_bit_cast(half8, b0), acc0, 0, 0, 0);
    }

    // ---- epilogue (C/D: col=lane&15, row=kq*4+r) ----
    const int col = lane & 15;
    const int h0 = 16 * w + col;
    const float bv0 = bias[h0];

    if (!head_out) {
        // layer 1: bias + relu + f16 store
#pragma unroll
        for (int r = 0; r < 4; ++r) {
            const size_t nrow = ((size_t)blk * 16 + kq * 4 + r) * DIM;
            out[nrow + h0] = f2h(fmaxf(acc0[r] + bv0, 0.f));
        }
    } else {
        // layer 2 + head: relu'd h dot out_w, reduce, sigmoid (no h2 roundtrip)
        const float w0 = outw[h0];
        float part[4];
#pragma unroll
        for (int r = 0; r < 4; ++r) {
            part[r] = fmaxf(acc0[r] + bv0, 0.f) * w0;
#pragma unroll
            for (int d = 1; d < 16; d <<= 1)
                part[r] += __shfl_xor(part[r], d, 16);   // sum over 16 col-lanes
        }
        __syncthreads();                 // all A16 reads done; reuse LDS
        float* hp = (float*)A16;         // hp[node_local][wave]
        if (col == 0) {
#pragma unroll
            for (int r = 0; r < 4; ++r) hp[(kq * 4 + r) * 8 + w] = part[r];
        }
        __syncthreads();
        if (tid < 16) {
            float vsum = outb[0];
#pragma unroll
            for (int k = 0; k < 8; ++k) vsum += hp[tid * 8 + k];
            head_out[blk * 16 + tid] = 1.0f / (1.0f + __expf(-vsum));
        }
    }
}

// ---------------------------------------------------------------- launch ----
extern "C" void kernel_launch(void* const* d_in, const int* in_sizes, int n_in,
                              void* d_out, int out_size, void* d_ws, size_t ws_size,
                              hipStream_t stream) {
    const float* x      = (const float*)d_in[0];
    const int*   ei     = (const int*)d_in[1];
    const int*   et     = (const int*)d_in[2];
    const float* Wrel1  = (const float*)d_in[3];
    const float* Wroot1 = (const float*)d_in[4];
    const float* b1     = (const float*)d_in[5];
    const float* Wrel2  = (const float*)d_in[6];
    const float* Wroot2 = (const float*)d_in[7];
    const float* b2     = (const float*)d_in[8];
    const float* outw   = (const float*)d_in[9];
    const float* outb   = (const float*)d_in[10];
    const int* src = ei;
    const int* dst = ei + NEDGES;

    // workspace layout (~68 MB, 16B-aligned chunks)
    char* ws = (char*)d_ws;
    int*            cnt    = (int*)(ws + 0);                     //  3,200,000
    int*            bsum   = (int*)(ws + 3200000);               //      4,096
    int*            segend = (int*)(ws + 3204096);               //  3,200,000
    int*            einfo  = (int*)(ws + 6404096);               //  6,400,256 (+pad)
    unsigned short* xh     = (unsigned short*)(ws + 12804352);   // 25,600,000
    unsigned short* h1     = (unsigned short*)(ws + 38404352);   // 25,600,000
    unsigned short* Wp1    = (unsigned short*)(ws + 64004352);   //    294,912
    unsigned short* Wp2    = (unsigned short*)(ws + 64299264);   //    294,912
    float*          inv    = (float*)(ws + 64594176);            //  3,200,000
    // end: 67,794,176 B

    hipMemsetAsync(cnt, 0, (size_t)NSEG * 4, stream);
    hipMemsetAsync(einfo + NEDGES, 0, 256, stream);   // zero pad for pipeline overrun
    count_cvt<<<CVT_BLKS + PACK_BLKS, 256, 0, stream>>>(dst, et, cnt, x, xh,
                                                        Wrel1, Wroot1, Wrel2, Wroot2,
                                                        Wp1, Wp2);
    scan_pass1<<<NSCAN, 256, 0, stream>>>(cnt, bsum, inv);
    scan_pass2<<<1, 64, 0, stream>>>(bsum);
    scan_pass3<<<NSCAN, 256, 0, stream>>>(cnt, bsum, segend);
    bucket_kernel<<<(NEDGES + 255) / 256, 256, 0, stream>>>(src, dst, et, segend, einfo);

    fused_layer<<<NNODES / 16, 512, 0, stream>>>(xh, segend, einfo, Wp1, b1, inv,
                                                 h1, nullptr, nullptr, nullptr);
    fused_layer<<<NNODES / 16, 512, 0, stream>>>(h1, segend, einfo, Wp2, b2, inv,
                                                 nullptr, outw, outb, (float*)d_out);
}